// Round 9
// baseline (1352.625 us; speedup 1.0000x reference)
//
#include <hip/hip_runtime.h>
#include <hip/hip_bf16.h>

typedef __hip_bfloat16 bf16;
typedef short short8v __attribute__((ext_vector_type(8)));
typedef float float4v __attribute__((ext_vector_type(4)));

static __device__ __forceinline__ float b2f(bf16 x){ return __bfloat162float(x); }

// dtype-flexible input load: isbf ? bf16[i] : f32[i]
static __device__ __forceinline__ float ldin(const void* p, size_t i, bool isbf) {
  return isbf ? b2f(((const bf16*)p)[i]) : ((const float*)p)[i];
}

static __device__ __forceinline__ unsigned short f2bu(float f) {
  bf16 h = __float2bfloat16(f);
  return *reinterpret_cast<unsigned short*>(&h);
}

#define CDIV(a,b) (((a)+(b)-1)/(b))

// Model constants
#define NB   4
#define NSL  50
#define HWT  256
#define NT   306     // NSL + HWT
#define DIM  512
#define NH   8
#define FF   2048
#define RPP  28100   // mixed rel-pos pairs per batch
#define PCH  56200   // rel-pos chunk (2 chunks of NB*RPP/2)

// decode mixed-pair index q (0..RPP-1) -> (i,j)
static __device__ __forceinline__ void rp_decode(int q, int& i, int& j) {
  if (q < 15300) { i = q / NT; j = q % NT; }
  else { int r = q - 15300; i = NSL + r / NSL; j = r % NSL; }
}

// ---------------------------------------------------------------------------
// dtype detector (bf16 vs f32 served data); flag=1 means bf16.
// ---------------------------------------------------------------------------
__global__ void detect_k(const void* p, int* flag) {
  const unsigned short* u = (const unsigned short*)p;
  int t = threadIdx.x;
  int e = (u[t] >> 7) & 0xFF;
  __shared__ int anybad;
  if (t == 0) anybad = 0;
  __syncthreads();
  if (e >= 0x88) atomicOr(&anybad, 1);
  __syncthreads();
  if (t == 0) *flag = anybad ? 0 : 1;
}

// ---------------------------------------------------------------------------
// Batched weight transpose: all 17 weights in ONE launch.
// W[K,N] (bf16 or f32) -> WT[N,K] bf16; K,N multiples of 64; L layer slices.
// ---------------------------------------------------------------------------
struct WtArgs {
  const void* W[17];
  unsigned long long wto[17];
  int K[17], N[17];
  int base[18];
};

__global__ __launch_bounds__(256) void wtrans_all_k(WtArgs a, unsigned short* __restrict__ WT,
                                                    const int* __restrict__ flagp) {
  const bool isbf = *flagp != 0;
  int bid = blockIdx.x;
  int idx = 0;
#pragma unroll
  for (int i = 1; i < 17; ++i) if (bid >= a.base[i]) idx = i;
  int t0 = bid - a.base[idx];
  const int K = a.K[idx], N = a.N[idx];
  const int tilesN = N >> 6;
  const int perLayer = tilesN * (K >> 6);
  const int layer = t0 / perLayer, rem = t0 % perLayer;
  const int n0 = (rem % tilesN) * 64, k0 = (rem / tilesN) * 64;
  const void* W = a.W[idx];
  unsigned short* dst0 = WT + a.wto[idx];
  const size_t slice = (size_t)K * N * layer;

  __shared__ unsigned short S[64 * 72];
  int t = threadIdx.x;
  int kk = t >> 4, nn = (t & 15) * 4;
#pragma unroll
  for (int r = 0; r < 4; ++r) {
    int k = k0 + kk + r * 16;
    unsigned short v[4];
    if (isbf) {
      ushort4 u = *(const ushort4*)((const unsigned short*)W + slice + (size_t)k * N + n0 + nn);
      v[0]=u.x; v[1]=u.y; v[2]=u.z; v[3]=u.w;
    } else {
      float4 f = *(const float4*)((const float*)W + slice + (size_t)k * N + n0 + nn);
      v[0]=f2bu(f.x); v[1]=f2bu(f.y); v[2]=f2bu(f.z); v[3]=f2bu(f.w);
    }
#pragma unroll
    for (int i = 0; i < 4; ++i) S[(nn + i) * 72 + kk + r * 16] = v[i];
  }
  __syncthreads();
  int nr = t >> 2, kc = (t & 3) * 16;
  short8v s0 = *(const short8v*)&S[nr * 72 + kc];
  short8v s1 = *(const short8v*)&S[nr * 72 + kc + 8];
  unsigned short* dst = dst0 + slice + (size_t)(n0 + nr) * K + k0 + kc;
  *(short8v*)dst = s0;
  *(short8v*)(dst + 8) = s1;
}

// ---------------------------------------------------------------------------
// MFMA bf16 GEMM body v3: BK=64 (8 MFMA per barrier pair), W TRANSPOSED as
// WT[N,K] bf16. Coalesced k-contig 32B/thread staging + register prefetch.
// mode: 0=store, 1=accumulate, 2=atomicAdd (K-split). bias added iff kbeg==0.
// act: 0 none, 1 relu, 2 gelu(tanh), 3 silu. N%64==0, K%64==0.
// ---------------------------------------------------------------------------
#define LDK 72
static __device__ __forceinline__ void gemm_body2(
    const void* __restrict__ A, int aty,
    const unsigned short* __restrict__ WT,
    const void* __restrict__ bias, size_t boff,
    void* __restrict__ C, int oty,
    int M, int N, int K, int kbeg, int kend,
    int act, int mode, bool isbf)
{
  __shared__ unsigned short As[64 * LDK];
  __shared__ unsigned short Bs[64 * LDK];
  const int tid = threadIdx.x;
  const int lane = tid & 63, wave = tid >> 6;
  const int quad = lane >> 4, ti = lane & 15;
  const int wm = (wave & 1) * 32, wn = (wave >> 1) * 32;
  const int bm = blockIdx.y * 64, bn = blockIdx.x * 64;
  const int srow = tid >> 2, sch = (tid & 3) * 16;

  unsigned short ha[16], hb[16];
  const int gm = bm + srow;
  const bool aok = gm < M;
  const unsigned short* Abf = (const unsigned short*)A + (size_t)gm * K;
  const float*          Af  = (const float*)A + (size_t)gm * K;
  const unsigned short* Bp  = WT + (size_t)(bn + srow) * K;

  auto fetchA = [&](int k0) {
    if (aok) {
      if (aty) {
        const ushort4* ap = (const ushort4*)(Abf + k0 + sch);
#pragma unroll
        for (int i = 0; i < 4; ++i) {
          ushort4 u = ap[i];
          ha[i*4+0]=u.x; ha[i*4+1]=u.y; ha[i*4+2]=u.z; ha[i*4+3]=u.w;
        }
      } else {
        const float4* ap = (const float4*)(Af + k0 + sch);
#pragma unroll
        for (int i = 0; i < 4; ++i) {
          float4 f = ap[i];
          ha[i*4+0]=f2bu(f.x); ha[i*4+1]=f2bu(f.y); ha[i*4+2]=f2bu(f.z); ha[i*4+3]=f2bu(f.w);
        }
      }
    } else {
#pragma unroll
      for (int i = 0; i < 16; ++i) ha[i] = 0;
    }
  };
  auto fetchB = [&](int k0) {
    const ushort4* bp = (const ushort4*)(Bp + k0 + sch);
#pragma unroll
    for (int i = 0; i < 4; ++i) {
      ushort4 u = bp[i];
      hb[i*4+0]=u.x; hb[i*4+1]=u.y; hb[i*4+2]=u.z; hb[i*4+3]=u.w;
    }
  };

  float4v acc00 = {0,0,0,0}, acc01 = {0,0,0,0}, acc10 = {0,0,0,0}, acc11 = {0,0,0,0};
  fetchA(kbeg); fetchB(kbeg);
  for (int k0 = kbeg; k0 < kend; k0 += 64) {
    *(short8v*)&As[srow * LDK + sch]     = *(short8v*)ha;
    *(short8v*)&As[srow * LDK + sch + 8] = *(short8v*)(ha + 8);
    *(short8v*)&Bs[srow * LDK + sch]     = *(short8v*)hb;
    *(short8v*)&Bs[srow * LDK + sch + 8] = *(short8v*)(hb + 8);
    __syncthreads();
    if (k0 + 64 < kend) { fetchA(k0 + 64); fetchB(k0 + 64); }
#pragma unroll
    for (int ks = 0; ks < 2; ++ks) {
      short8v a0 = *reinterpret_cast<const short8v*>(&As[(wm + ti)      * LDK + ks * 32 + quad * 8]);
      short8v a1 = *reinterpret_cast<const short8v*>(&As[(wm + 16 + ti) * LDK + ks * 32 + quad * 8]);
      short8v b0 = *reinterpret_cast<const short8v*>(&Bs[(wn + ti)      * LDK + ks * 32 + quad * 8]);
      short8v b1 = *reinterpret_cast<const short8v*>(&Bs[(wn + 16 + ti) * LDK + ks * 32 + quad * 8]);
      acc00 = __builtin_amdgcn_mfma_f32_16x16x32_bf16(a0, b0, acc00, 0, 0, 0);
      acc01 = __builtin_amdgcn_mfma_f32_16x16x32_bf16(a0, b1, acc01, 0, 0, 0);
      acc10 = __builtin_amdgcn_mfma_f32_16x16x32_bf16(a1, b0, acc10, 0, 0, 0);
      acc11 = __builtin_amdgcn_mfma_f32_16x16x32_bf16(a1, b1, acc11, 0, 0, 0);
    }
    __syncthreads();
  }

  float4v accs[2][2] = {{acc00, acc01}, {acc10, acc11}};
#pragma unroll
  for (int mi = 0; mi < 2; ++mi) {
#pragma unroll
    for (int ni = 0; ni < 2; ++ni) {
      int row0 = bm + wm + mi * 16 + quad * 4;
      int col  = bn + wn + ni * 16 + ti;
      float bv = (bias && kbeg == 0) ? ldin(bias, boff + col, isbf) : 0.f;
#pragma unroll
      for (int r = 0; r < 4; ++r) {
        int row = row0 + r;
        if (row >= M) continue;
        float v = accs[mi][ni][r] + bv;
        if (act == 1) v = fmaxf(v, 0.f);
        else if (act == 2) {
          float u = 0.7978845608028654f * (v + 0.044715f * v * v * v);
          v = 0.5f * v * (1.f + tanhf(u));
        } else if (act == 3) {
          v = v / (1.f + expf(-v));
        }
        size_t idx = (size_t)row * N + col;
        if (oty) ((bf16*)C)[idx] = __float2bfloat16(v);
        else {
          float* Cf = (float*)C;
          if (mode == 2) atomicAdd(&Cf[idx], v);
          else if (mode == 1) Cf[idx] += v;
          else Cf[idx] = v;
        }
      }
    }
  }
}

__global__ __launch_bounds__(256) void gemm_mfma(
    const void* A, int aty, const unsigned short* WT, size_t woff,
    const void* bias, size_t boff, void* C, int oty,
    int M, int N, int K, int act, int accum, int zsplit, const int* __restrict__ flagp)
{
  int ksz = K / zsplit;
  int kbeg = blockIdx.z * ksz;
  int mode = zsplit > 1 ? 2 : (accum ? 1 : 0);
  gemm_body2(A, aty, WT + woff, bias, boff, C, oty, M, N, K, kbeg, kbeg + ksz,
             act, mode, *flagp != 0);
}

// 3 GEMMs sharing A/shapes (QKV); blockIdx.z selects job
__global__ __launch_bounds__(256) void gemm_mfma_tri(
    const void* A, int aty, const unsigned short* WT, size_t o0, size_t o1, size_t o2,
    void* C0, void* C1, void* C2, int oty, int M, int N, int K,
    const int* __restrict__ flagp)
{
  size_t o = blockIdx.z == 0 ? o0 : (blockIdx.z == 1 ? o1 : o2);
  void* C = blockIdx.z == 0 ? C0 : (blockIdx.z == 1 ? C1 : C2);
  gemm_body2(A, aty, WT + o, nullptr, 0, C, oty, M, N, K, 0, K, 0, 0, *flagp != 0);
}

// 2 GEMMs, separate A/W/bias/C, shared shapes
__global__ __launch_bounds__(256) void gemm_mfma_duo(
    const void* A0, const void* A1, int aty, const unsigned short* WT, size_t o0, size_t o1,
    const void* bias0, const void* bias1, void* C0, void* C1, int oty,
    int M, int N, int K, const int* __restrict__ flagp)
{
  const void* A = blockIdx.z ? A1 : A0;
  size_t o = blockIdx.z ? o1 : o0;
  const void* bias = blockIdx.z ? bias1 : bias0;
  void* C = blockIdx.z ? C1 : C0;
  gemm_body2(A, aty, WT + o, bias, 0, C, oty, M, N, K, 0, K, 0, 0, *flagp != 0);
}

// ---------------------------------------------------------------------------
// slot coords projection: SC[row,0:2] = SLOTS[row,:] @ s2c_w + s2c_b
// ---------------------------------------------------------------------------
__global__ void s2c_k(const float* __restrict__ slots, const void* __restrict__ w,
                      const void* __restrict__ bv, float* __restrict__ sc,
                      const int* __restrict__ flagp) {
  const bool isbf = *flagp != 0;
  int row = blockIdx.x, t = threadIdx.x;
  const float* x = slots + (size_t)row * DIM;
  float v0 = x[t], v1 = x[t + 256];
  float a0 = v0 * ldin(w, 2 * t, isbf)     + v1 * ldin(w, 2 * (t + 256), isbf);
  float a1 = v0 * ldin(w, 2 * t + 1, isbf) + v1 * ldin(w, 2 * (t + 256) + 1, isbf);
  __shared__ float r0[256], r1[256];
  r0[t] = a0; r1[t] = a1;
  __syncthreads();
  for (int o = 128; o > 0; o >>= 1) {
    if (t < o) { r0[t] += r0[t + o]; r1[t] += r1[t + o]; }
    __syncthreads();
  }
  if (t == 0) {
    sc[row * 2]     = r0[0] + ldin(bv, 0, isbf);
    sc[row * 2 + 1] = r1[0] + ldin(bv, 1, isbf);
  }
}

// ---------------------------------------------------------------------------
// Patch extraction (im2col) -> bf16
// ---------------------------------------------------------------------------
__global__ void patchify_k(const void* __restrict__ img, unsigned short* __restrict__ xp,
                           const int* __restrict__ flagp) {
  const bool isbf = *flagp != 0;
  int i = blockIdx.x * 256 + threadIdx.x;
  if (i >= NB * HWT * 768) return;
  int col = i % 768, row = i / 768;
  int c = col % 3, p2 = (col / 3) & 15, p1 = col / 48;
  int w = row & 15, h = (row >> 4) & 15, b = row >> 8;
  xp[i] = f2bu(ldin(img, (((size_t)(b * 3 + c) * 256 + h * 16 + p1) * 256) + w * 16 + p2, isbf));
}

__global__ void addpos_k(float* __restrict__ tok, const void* __restrict__ hp,
                         const void* __restrict__ wp, const int* __restrict__ flagp) {
  const bool isbf = *flagp != 0;
  int i = blockIdx.x * 256 + threadIdx.x;
  if (i >= NB * HWT * DIM) return;
  int d = i & 511;
  int row = i >> 9;
  int w = row & 15, h = (row >> 4) & 15;
  tok[i] += ldin(hp, h * DIM + d, isbf) + ldin(wp, w * DIM + d, isbf);
}

// ---------------------------------------------------------------------------
// LayerNorm (bf16 out) / RMSNorm (bf16 out) over 512-dim rows
// ---------------------------------------------------------------------------
__global__ void ln512_k(const float* __restrict__ X, const void* __restrict__ g,
                        const void* __restrict__ b, unsigned short* __restrict__ Y,
                        const int* __restrict__ flagp) {
  const bool isbf = *flagp != 0;
  int row = blockIdx.x, t = threadIdx.x;
  const float* x = X + (size_t)row * DIM;
  float v0 = x[t], v1 = x[t + 256];
  __shared__ float rs[256], rq[256];
  rs[t] = v0 + v1; rq[t] = v0 * v0 + v1 * v1;
  __syncthreads();
  for (int o = 128; o > 0; o >>= 1) {
    if (t < o) { rs[t] += rs[t + o]; rq[t] += rq[t + o]; }
    __syncthreads();
  }
  float mean = rs[0] * (1.f / 512.f);
  float var  = rq[0] * (1.f / 512.f) - mean * mean;
  float inv  = rsqrtf(var + 1e-5f);
  unsigned short* y = Y + (size_t)row * DIM;
  y[t]       = f2bu((v0 - mean) * inv * ldin(g, t, isbf)       + ldin(b, t, isbf));
  y[t + 256] = f2bu((v1 - mean) * inv * ldin(g, t + 256, isbf) + ldin(b, t + 256, isbf));
}

__global__ void rms512_k(const float* __restrict__ X, const void* __restrict__ g,
                         int goff, unsigned short* __restrict__ Y, const int* __restrict__ flagp) {
  const bool isbf = *flagp != 0;
  int row = blockIdx.x, t = threadIdx.x;
  const float* x = X + (size_t)row * DIM;
  float v0 = x[t], v1 = x[t + 256];
  __shared__ float rq[256];
  rq[t] = v0 * v0 + v1 * v1;
  __syncthreads();
  for (int o = 128; o > 0; o >>= 1) {
    if (t < o) rq[t] += rq[t + o];
    __syncthreads();
  }
  float nrm = sqrtf(rq[0]);
  float sc = 22.62741699796952f / fmaxf(nrm, 1e-12f);
  unsigned short* y = Y + (size_t)row * DIM;
  y[t]       = f2bu(v0 * sc * ldin(g, goff + t, isbf));
  y[t + 256] = f2bu(v1 * sc * ldin(g, goff + t + 256, isbf));
}

// ---------------------------------------------------------------------------
// Slot attention
// ---------------------------------------------------------------------------
__global__ void slots_init_k(const void* __restrict__ mu, const void* __restrict__ ls,
                             const void* __restrict__ noise, float* __restrict__ slots,
                             const int* __restrict__ flagp) {
  const bool isbf = *flagp != 0;
  int i = blockIdx.x * 256 + threadIdx.x;
  if (i >= NB * NSL * DIM) return;
  int d = i & 511;
  slots[i] = ldin(mu, d, isbf) + expf(ldin(ls, d, isbf)) * ldin(noise, i, isbf);
}

// Fused slot-attention core: dots -> softmax(over slots) -> +1e-8 renorm ->
// upd = attn @ v. One block per (b,h); 16 blocks, 256 threads.
__global__ __launch_bounds__(256) void slot_core_k(
    const float* __restrict__ QB, const float* __restrict__ KB,
    const float* __restrict__ VB, float* __restrict__ UPD)
{
  const int b = blockIdx.x >> 2, h = blockIdx.x & 3;
  __shared__ float qs[NSL * 68];
  __shared__ float S[NSL * 260];
  __shared__ float rs[NSL];
  const int t = threadIdx.x;

  // stage q (50 x 64)
  for (int e = t; e < NSL * 64; e += 256) {
    int i = e >> 6, d = e & 63;
    qs[i * 68 + d] = QB[((size_t)(b * NSL + i)) * 256 + h * 64 + d];
  }
  __syncthreads();

  // dots: thread j owns column j
  {
    const float* kr = KB + ((size_t)(b * HWT + t)) * 256 + h * 64;
    float kv[64];
#pragma unroll
    for (int d = 0; d < 64; ++d) kv[d] = kr[d];
    for (int i = 0; i < NSL; ++i) {
      float s = 0.f;
#pragma unroll
      for (int d = 0; d < 64; ++d) s = fmaf(qs[i * 68 + d], kv[d], s);
      S[i * 260 + t] = s * 0.125f;
    }
  }
  __syncthreads();

  // softmax over slots (i) per column j; then +1e-8
  {
    float m = -1e30f;
    for (int i = 0; i < NSL; ++i) m = fmaxf(m, S[i * 260 + t]);
    float s = 0.f;
    for (int i = 0; i < NSL; ++i) { float e = __expf(S[i * 260 + t] - m); S[i * 260 + t] = e; s += e; }
    float inv = 1.f / s;
    for (int i = 0; i < NSL; ++i) S[i * 260 + t] = S[i * 260 + t] * inv + 1e-8f;
  }
  __syncthreads();

  // row sums (renorm denominators)
  {
    int lane = t & 63, wv = t >> 6;
    for (int i = wv; i < NSL; i += 4) {
      float s = S[i * 260 + lane] + S[i * 260 + lane + 64] +
                S[i * 260 + lane + 128] + S[i * 260 + lane + 192];
      s += __shfl_xor(s, 1);  s += __shfl_xor(s, 2);  s += __shfl_xor(s, 4);
      s += __shfl_xor(s, 8);  s += __shfl_xor(s, 16); s += __shfl_xor(s, 32);
      if (lane == 0) rs[i] = s;
    }
  }
  __syncthreads();

  // upd[i][d] = (1/rs[i]) * sum_j S[i][j] * v[j][d]; group g handles rows g::4
  {
    int d = t & 63, g = t >> 6;
    float acc[13] = {};
    int cnt = (NSL - g + 3) >> 2;
    for (int j = 0; j < HWT; ++j) {
      float v = VB[((size_t)(b * HWT + j)) * 256 + h * 64 + d];
      int ii = g;
#pragma unroll
      for (int c = 0; c < 13; ++c) {
        if (c < cnt) acc[c] = fmaf(S[ii * 260 + j], v, acc[c]);
        ii += 4;
      }
    }
    int ii = g;
#pragma unroll
    for (int c = 0; c < 13; ++c) {
      if (c < cnt)
        UPD[((size_t)(b * NSL + ii)) * 256 + h * 64 + d] = acc[c] / rs[ii];
      ii += 4;
    }
  }
}

// in-place safe (elementwise)
__global__ void gru_k(const float* __restrict__ gx, const float* __restrict__ gh,
                      float* __restrict__ slots) {
  int i = blockIdx.x * 256 + threadIdx.x;
  if (i >= NB * NSL * DIM) return;
  int row = i >> 9, d = i & 511;
  size_t b3 = (size_t)row * 1536;
  float xr = gx[b3 + d], xz = gx[b3 + 512 + d], xn = gx[b3 + 1024 + d];
  float hr = gh[b3 + d], hz = gh[b3 + 512 + d], hn = gh[b3 + 1024 + d];
  float r = 1.f / (1.f + expf(-(xr + hr)));
  float z = 1.f / (1.f + expf(-(xz + hz)));
  float n = tanhf(xn + r * hn);
  float prev = slots[i];
  slots[i] = (1.f - z) * n + z * prev;
}

// ---------------------------------------------------------------------------
// Rel-pos bias
// ---------------------------------------------------------------------------
__global__ void build_coords_k(const float* __restrict__ sc, float* __restrict__ coords) {
  int i = blockIdx.x * 256 + threadIdx.x;
  if (i >= NB * NT) return;
  int b = i / NT, n = i % NT;
  float cx, cy;
  if (n < NSL) { cx = sc[(b * NSL + n) * 2]; cy = sc[(b * NSL + n) * 2 + 1]; }
  else { int t = n - NSL; cx = (float)(t >> 4); cy = (float)(t & 15); }
  coords[i * 2] = cx; coords[i * 2 + 1] = cy;
}

__global__ void relpos_table_k(const void* w1, const void* b1, const void* w2,
                               const void* b2, const void* w3, const void* b3,
                               float* __restrict__ tab, const int* __restrict__ flagp) {
  const bool isbf = *flagp != 0;
  int blk = blockIdx.x;  // 961
  float r0 = (float)(blk / 31 - 15), r1 = (float)(blk % 31 - 15);
  int t = threadIdx.x;
  __shared__ float h1[128], h2[128];
  float a = fmaf(r0, ldin(w1, t, isbf), fmaf(r1, ldin(w1, 128 + t, isbf), ldin(b1, t, isbf)));
  h1[t] = a / (1.f + expf(-a));
  __syncthreads();
  float s = ldin(b2, t, isbf);
#pragma unroll 4
  for (int k = 0; k < 128; ++k) s = fmaf(h1[k], ldin(w2, k * 128 + t, isbf), s);
  h2[t] = s / (1.f + expf(-s));
  __syncthreads();
  if (t < 8) {
    float o = ldin(b3, t, isbf);
#pragma unroll 4
    for (int k = 0; k < 128; ++k) o = fmaf(h2[k], ldin(w3, k * 8 + t, isbf), o);
    tab[blk * 8 + t] = o;
  }
}

__global__ void bias_fill_k(const float* __restrict__ tab, float* __restrict__ bias) {
  int i = blockIdx.x * 256 + threadIdx.x;
  if (i >= NB * NH * HWT * HWT) return;
  int jj = i & 255, ii = (i >> 8) & 255, h = (i >> 16) & 7, b = i >> 19;
  int di = (ii >> 4) - (jj >> 4) + 15;
  int dj = (ii & 15) - (jj & 15) + 15;
  bias[(((size_t)(b * NH + h) * NT) + NSL + ii) * NT + NSL + jj] = tab[(di * 31 + dj) * 8 + h];
}

// layer1 silu -> H1 bf16 [pcount,128], chunked
__global__ void rp_l1_k(const float* __restrict__ coords, const void* w1, const void* b1,
                        unsigned short* __restrict__ H, int pbase, int pcount,
                        const int* __restrict__ flagp) {
  const bool isbf = *flagp != 0;
  int idx = blockIdx.x * 256 + threadIdx.x;
  if (idx >= pcount * 128) return;
  int pl = idx >> 7, u = idx & 127;
  int p = pbase + pl;
  int q = p % RPP, bb = p / RPP;
  int ii, jj;
  rp_decode(q, ii, jj);
  float r0 = coords[(bb * NT + ii) * 2]     - coords[(bb * NT + jj) * 2];
  float r1 = coords[(bb * NT + ii) * 2 + 1] - coords[(bb * NT + jj) * 2 + 1];
  float a = fmaf(r0, ldin(w1, u, isbf), fmaf(r1, ldin(w1, 128 + u, isbf), ldin(b1, u, isbf)));
  H[(size_t)pl * 128 + u] = f2bu(a / (1.f + expf(-a)));
}

// layer3 (128->8) + scatter. 32 pairs/block, 8 threads/pair.
__global__ __launch_bounds__(256) void rp_l3_k(
    const unsigned short* __restrict__ H2, const void* w3, const void* b3,
    float* __restrict__ bias, int pbase, int pcount, const int* __restrict__ flagp) {
  const bool isbf = *flagp != 0;
  __shared__ float W3s[128 * 8];
  int t = threadIdx.x;
  for (int e = t; e < 1024; e += 256) W3s[e] = ldin(w3, e, isbf);
  __syncthreads();
  int pl = blockIdx.x * 32 + (t >> 3), hh = t & 7;
  if (pl >= pcount) return;
  int p = pbase + pl;
  int q = p % RPP, bb = p / RPP;
  int ii, jj;
  rp_decode(q, ii, jj);
  float s = ldin(b3, hh, isbf);
  const unsigned short* hrow = H2 + (size_t)pl * 128;
#pragma unroll 8
  for (int k = 0; k < 128; ++k) {
    bf16 hv = *reinterpret_cast<const bf16*>(&hrow[k]);
    s = fmaf(b2f(hv), W3s[k * 8 + hh], s);
  }
  bias[((size_t)(bb * NH + hh) * NT + ii) * NT + jj] = s;
}

// ---------------------------------------------------------------------------
// Transformer pieces
// ---------------------------------------------------------------------------
__global__ void build_x_k(const float* __restrict__ slots, const float* __restrict__ tok,
                          float* __restrict__ x) {
  int i = blockIdx.x * 256 + threadIdx.x;
  if (i >= NB * NT * DIM) return;
  int d = i & 511, n = (i >> 9) % NT, b = i / (NT * DIM);
  x[i] = (n < NSL) ? slots[((size_t)(b * NSL + n)) * DIM + d]
                   : tok[((size_t)(b * HWT + (n - NSL))) * DIM + d];
}

// ---------------------------------------------------------------------------
// Fused attention: per block = 32 q-rows x one (b,h). S = QK^T*0.125 + bias
// (f32 LDS), in-block softmax (8 lanes/row), P bf16 in place, O = P V.
// grid (10, 32). LDS ~56 KB.
// ---------------------------------------------------------------------------
__global__ __launch_bounds__(256) void attn_fused_k(
    const unsigned short* __restrict__ Qb, const unsigned short* __restrict__ Kb,
    const unsigned short* __restrict__ Vb, const float* __restrict__ bias,
    unsigned short* __restrict__ Ob)
{
  const int bh = blockIdx.y, b = bh >> 3, h = bh & 7;
  const int i0 = blockIdx.x * 32;
  __shared__ unsigned short Qs[32 * 72];
  __shared__ unsigned short Ks[64 * 72];
  __shared__ float S[32 * 332];
  unsigned short* P = (unsigned short*)S;   // bf16 prob, row stride 664 shorts

  const int tid = threadIdx.x;
  const int lane = tid & 63, wave = tid >> 6, quad = lane >> 4, ti = lane & 15;
  const int mi = wave & 1, nh = wave >> 1;

  // ---- load Q tile (32 x 64) ----
  {
    int r = tid >> 3, c = (tid & 7) * 8;
    int gi = i0 + r;
    ushort4 u0 = {0,0,0,0}, u1 = {0,0,0,0};
    if (gi < NT) {
      const ushort4* p = (const ushort4*)(Qb + ((size_t)(b * NT + gi)) * DIM + h * 64 + c);
      u0 = p[0]; u1 = p[1];
    }
    *(ushort4*)&Qs[r * 72 + c] = u0;
    *(ushort4*)&Qs[r * 72 + c + 4] = u1;
  }

  // ---- phase 1: scores ----
  for (int kt = 0; kt < 5; ++kt) {
    __syncthreads();
    {
      int kr = tid >> 2, c = (tid & 3) * 16;
      int gj = kt * 64 + kr;
      ushort4 v[4] = {{0,0,0,0},{0,0,0,0},{0,0,0,0},{0,0,0,0}};
      if (gj < NT) {
        const ushort4* p = (const ushort4*)(Kb + ((size_t)(b * NT + gj)) * DIM + h * 64 + c);
#pragma unroll
        for (int i = 0; i < 4; ++i) v[i] = p[i];
      }
#pragma unroll
      for (int i = 0; i < 4; ++i) *(ushort4*)&Ks[kr * 72 + c + i * 4] = v[i];
    }
    __syncthreads();
#pragma unroll
    for (int ntl = 0; ntl < 2; ++ntl) {
      int nt = nh * 2 + ntl;
      float4v acc = {0,0,0,0};
#pragma unroll
      for (int ks = 0; ks < 2; ++ks) {
        short8v a  = *(const short8v*)&Qs[(mi * 16 + ti) * 72 + ks * 32 + quad * 8];
        short8v bb = *(const short8v*)&Ks[(nt * 16 + ti) * 72 + ks * 32 + quad * 8];
        acc = __builtin_amdgcn_mfma_f32_16x16x32_bf16(a, bb, acc, 0, 0, 0);
      }
      int colL = kt * 64 + nt * 16 + ti;
      int row0 = mi * 16 + quad * 4;
#pragma unroll
      for (int r = 0; r < 4; ++r) {
        int row_g = i0 + row0 + r;
        float val;
        if (colL < NT) {
          float bv = (row_g < NT) ? bias[((size_t)bh * NT + row_g) * NT + colL] : 0.f;
          val = acc[r] * 0.125f + bv;
        } else val = -1e30f;
        S[(row0 + r) * 332 + colL] = val;
      }
    }
  }
  __syncthreads();

  // ---- phase 2: softmax (rows in regs), write P bf16 in place ----
  {
    int rl = tid >> 3, sub = tid & 7;
    float sv[40];
#pragma unroll
    for (int k = 0; k < 40; ++k) sv[k] = S[rl * 332 + sub + k * 8];
    float m = -1e30f;
#pragma unroll
    for (int k = 0; k < 40; ++k) m = fmaxf(m, sv[k]);
    m = fmaxf(m, __shfl_xor(m, 1));
    m = fmaxf(m, __shfl_xor(m, 2));
    m = fmaxf(m, __shfl_xor(m, 4));
    float s = 0.f;
#pragma unroll
    for (int k = 0; k < 40; ++k) { float e = __expf(sv[k] - m); sv[k] = e; s += e; }
    s += __shfl_xor(s, 1);
    s += __shfl_xor(s, 2);
    s += __shfl_xor(s, 4);
    float inv = 1.f / s;
    __syncthreads();   // all S reads complete before bf16 overwrite
#pragma unroll
    for (int k = 0; k < 40; ++k) P[rl * 664 + sub + k * 8] = f2bu(sv[k] * inv);
  }

  // ---- phase 3: O = P V ----
  float4v oacc[2] = {{0,0,0,0},{0,0,0,0}};
  for (int vt = 0; vt < 5; ++vt) {
    __syncthreads();
    {
      int key = tid & 63, d0 = (tid >> 6) * 16;
      int gj = vt * 64 + key;
      unsigned short hv[16];
      if (gj < NT) {
        const ushort4* p = (const ushort4*)(Vb + ((size_t)(b * NT + gj)) * DIM + h * 64 + d0);
#pragma unroll
        for (int i = 0; i < 4; ++i) {
          ushort4 u = p[i];
          hv[i*4+0]=u.x; hv[i*4+1]=u.y; hv[i*4+2]=u.z; hv[i*4+3]=u.w;
        }
      } else {
#pragma unroll
        for (int i = 0; i < 16; ++i) hv[i] = 0;
      }
#pragma unroll
      for (int i = 0; i < 16; ++i) Ks[(d0 + i) * 72 + key] = hv[i];
    }
    __syncthreads();
#pragma unroll
    for (int ntl = 0; ntl < 2; ++ntl) {
      int nt = nh * 2 + ntl;
#pragma unroll
      for (int ks = 0; ks < 2; ++ks) {
        short8v a  = *(const short8v*)&P[(mi * 16 + ti) * 664 + vt * 64 + ks * 32 + quad * 8];
        short8v bb = *(const short8v*)&Ks[(nt * 16 + ti) * 72 + ks * 32 + quad * 8];
        oacc[ntl] = __builtin_amdgcn_mfma_f32_16x16x32_bf16(a, bb, oacc[ntl], 0, 0, 0);
      }
    }
  }

  // ---- write O ----
#pragma unroll
  for (int ntl = 0; ntl < 2; ++ntl) {
    int dim = nh * 32 + ntl * 16 + ti;
#pragma unroll
    for (int r = 0; r < 4; ++r) {
      int row_g = i0 + mi * 16 + quad * 4 + r;
      if (row_g < NT)
        Ob[((size_t)(b * NT + row_g)) * DIM + h * 64 + dim] = f2bu(oacc[ntl][r]);
    }
  }
}

__global__ void write_out_k(const float* __restrict__ tmp, void* __restrict__ out,
                            const int* __restrict__ flagp) {
  const bool isbf = *flagp != 0;
  int i = blockIdx.x * 256 + threadIdx.x;
  if (i >= NB * HWT * DIM) return;
  int d = i & 511, tt = (i >> 9) & 255, b = i / (HWT * DIM);
  float v = tmp[((size_t)(b * NT + NSL + tt)) * DIM + d];
  if (isbf) ((bf16*)out)[i] = __float2bfloat16(v);
  else      ((float*)out)[i] = v;
}

// ---------------------------------------------------------------------------
extern "C" void kernel_launch(void* const* d_in, const int* in_sizes, int n_in,
                              void* d_out, int out_size, void* d_ws, size_t ws_size,
                              hipStream_t stream) {
  const void* images        = d_in[0];
  const void* slot_noise    = d_in[1];
  const void* patch_w       = d_in[2];
  const void* patch_b       = d_in[3];
  const void* hpos          = d_in[4];
  const void* wpos          = d_in[5];
  const void* rp_w1         = d_in[6];
  const void* rp_b1         = d_in[7];
  const void* rp_w2         = d_in[8];
  const void* rp_b2         = d_in[9];
  const void* rp_w3         = d_in[10];
  const void* rp_b3         = d_in[11];
  const void* slots_mu      = d_in[12];
  const void* slots_logsig  = d_in[13];
  const void* sa_ln_in_g    = d_in[14];
  const void* sa_ln_in_b    = d_in[15];
  const void* sa_ln_sl_g    = d_in[16];
  const void* sa_ln_sl_b    = d_in[17];
  const void* sa_wq         = d_in[18];
  const void* sa_bq         = d_in[19];
  const void* sa_wk         = d_in[20];
  const void* sa_bk         = d_in[21];
  const void* sa_wv         = d_in[22];
  const void* sa_bv         = d_in[23];
  const void* sa_wo         = d_in[24];
  const void* sa_bo         = d_in[25];
  const void* gru_wih       = d_in[26];
  const void* gru_whh       = d_in[27];
  const void* gru_bih       = d_in[28];
  const void* gru_bhh       = d_in[29];
  const void* sa_ln_ff_g    = d_in[30];
  const void* sa_ln_ff_b    = d_in[31];
  const void* sa_mlp_w1     = d_in[32];
  const void* sa_mlp_b1     = d_in[33];
  const void* sa_mlp_w2     = d_in[34];
  const void* sa_mlp_b2     = d_in[35];
  const void* s2c_w         = d_in[36];
  const void* s2c_b         = d_in[37];
  const void* attn_g        = d_in[38];
  const void* wq            = d_in[39];
  const void* wk            = d_in[40];
  const void* wv            = d_in[41];
  const void* wo            = d_in[42];
  const void* ff_g          = d_in[43];
  const void* ff_w1         = d_in[44];
  const void* ff_b1         = d_in[45];
  const void* ff_w2         = d_in[46];
  const void* ff_b2         = d_in[47];
  const void* final_g       = d_in[48];
  const void* pred_w        = d_in[49];
  const void* pred_b        = d_in[50];

  float* ws = (float*)d_ws;
  int* FLAG = (int*)ws;
  size_t off = 16;
  auto alloc = [&](size_t n) { float* p = ws + off; off += (n + 15) & ~(size_t)15; return p; };
  float* TOK   = alloc((size_t)NB * HWT * DIM);
  unsigned short* INPB = (unsigned short*)alloc((size_t)NB * HWT * DIM / 2);
  float* KB    = alloc((size_t)NB * HWT * 256);
  float* VB    = alloc((size_t)NB * HWT * 256);
  float* SLOTS = alloc((size_t)NB * NSL * DIM);
  unsigned short* SLNB = (unsigned short*)alloc((size_t)NB * NSL * DIM / 2);
  float* QB    = alloc((size_t)NB * NSL * 256);
  float* UPD   = alloc((size_t)NB * NSL * 256);
  float* UPDP  = alloc((size_t)NB * NSL * DIM);
  unsigned short* HIDSB = (unsigned short*)alloc((size_t)NB * NSL * DIM / 2);
  float* SC    = alloc((size_t)NB * NSL * 2);
  float* CRD   = alloc((size_t)NB * NT * 2);
  float* TAB   = alloc((size_t)961 * 8);
  float* BIAS  = alloc((size_t)NB * NH * NT * NT);
  float* X     = alloc((size_t)NB * NT * DIM);
  // attention-region (contiguous; aliased by rel-pos H1/H2 chunks)
  unsigned short* HBB  = (unsigned short*)alloc((size_t)NB * NT * DIM / 2);
  unsigned short* QHB  = (unsigned short*)alloc((size_t)NB * NT * DIM / 2);
  unsigned short* KHB  = (unsigned short*)alloc((size_t)NB * NT * DIM / 2);
  unsigned short* VHB  = (unsigned short*)alloc((size_t)NB * NT * DIM / 2);
  float* SIM   = alloc((size_t)NB * NH * NT * NT);        // GRU-gate + rel-pos alias space
  unsigned short* OBB  = (unsigned short*)alloc((size_t)NB * NT * DIM / 2);
  unsigned short* FFHB = (unsigned short*)alloc((size_t)NB * NT * FF / 2);
  float* OUTT  = alloc((size_t)NB * NT * DIM);
  // aliases (dead-region reuse)
  unsigned short* XPB = (unsigned short*)OUTT;            // im2col; dead before head
  float* GX = SIM;                                        // GRU gates; dead before transformer
  float* GH = SIM + (size_t)NB * NSL * 1536;
  // transposed-weight arena (bf16 [N,K] per weight)
  const size_t oPatch = 0;
  const size_t oKw    = oPatch + (size_t)512 * 768;
  const size_t oVw    = oKw    + (size_t)256 * 512;
  const size_t oQw    = oVw    + (size_t)256 * 512;
  const size_t oWo    = oQw    + (size_t)256 * 512;
  const size_t oGih   = oWo    + (size_t)512 * 256;
  const size_t oGhh   = oGih   + (size_t)1536 * 512;
  const size_t oMlp1  = oGhh   + (size_t)1536 * 512;
  const size_t oMlp2  = oMlp1  + (size_t)512 * 512;
  const size_t oRp2   = oMlp2  + (size_t)512 * 512;
  const size_t oWq    = oRp2   + (size_t)128 * 128;
  const size_t oWk    = oWq    + (size_t)6 * 512 * 512;
  const size_t oWv    = oWk    + (size_t)6 * 512 * 512;
  const size_t oWol   = oWv    + (size_t)6 * 512 * 512;
  const size_t oFf1   = oWol   + (size_t)6 * 512 * 512;
  const size_t oFf2   = oFf1   + (size_t)6 * 512 * 2048;
  const size_t oPred  = oFf2   + (size_t)6 * 2048 * 512;
  const size_t wtTotal = oPred + (size_t)512 * 512;
  unsigned short* WTS = (unsigned short*)alloc((wtTotal + 1) / 2);
  (void)ws_size; (void)in_sizes; (void)n_in; (void)out_size;

#define GEMMM(A_, ATY_, WOFF_, BIAS_, BOFF_, C_, OTY_, M_, N_, K_, ACT_, ACC_, ZS_) \
  gemm_mfma<<<dim3((N_)/64, CDIV((M_),64), (ZS_)), 256, 0, stream>>>( \
      A_, ATY_, WTS, (size_t)(WOFF_), BIAS_, (size_t)(BOFF_), C_, OTY_, M_, N_, K_, ACT_, ACC_, ZS_, FLAG)

  const int MROW = NB * NT;   // 1224
  const int MS   = NB * NSL;  // 200

  // ---- dtype detection + batched weight transpose (1 launch) ----
  detect_k<<<1, 256, 0, stream>>>(images, FLAG);
  {
    WtArgs a;
    const void* Wp[17] = { patch_w, sa_wk, sa_wv, sa_wq, sa_wo, gru_wih, gru_whh,
                           sa_mlp_w1, sa_mlp_w2, rp_w2, wq, wk, wv, wo, ff_w1, ff_w2, pred_w };
    const size_t Oo[17] = { oPatch, oKw, oVw, oQw, oWo, oGih, oGhh,
                            oMlp1, oMlp2, oRp2, oWq, oWk, oWv, oWol, oFf1, oFf2, oPred };
    const int Kk[17] = {768,512,512,512,256,512,512,512,512,128,512,512,512,512,512,2048,512};
    const int Nn[17] = {512,256,256,256,512,1536,1536,512,512,128,512,512,512,512,2048,512,512};
    const int Ll[17] = {1,1,1,1,1,1,1,1,1,1,6,6,6,6,6,6,1};
    int acc = 0;
    for (int i = 0; i < 17; ++i) {
      a.W[i] = Wp[i]; a.wto[i] = Oo[i]; a.K[i] = Kk[i]; a.N[i] = Nn[i];
      a.base[i] = acc;
      acc += Ll[i] * (Kk[i] >> 6) * (Nn[i] >> 6);
    }
    a.base[17] = acc;
    wtrans_all_k<<<acc, 256, 0, stream>>>(a, WTS, FLAG);
  }

  // ---- patch embed (K-split 3, atomic into zeroed TOK) ----
  patchify_k<<<CDIV(NB*HWT*768, 256), 256, 0, stream>>>(images, XPB, FLAG);
  hipMemsetAsync(TOK, 0, (size_t)NB * HWT * DIM * sizeof(float), stream);
  GEMMM(XPB, 1, oPatch, patch_b, 0, TOK, 0, NB*HWT, DIM, 768, 0, 0, 3);
  addpos_k<<<CDIV(NB*HWT*DIM, 256), 256, 0, stream>>>(TOK, hpos, wpos, FLAG);

  // ---- slot attention: k, v ----
  ln512_k<<<NB*HWT, 256, 0, stream>>>(TOK, sa_ln_in_g, sa_ln_in_b, INPB, FLAG);
  gemm_mfma_duo<<<dim3(4, 16, 2), 256, 0, stream>>>(
      INPB, INPB, 1, WTS, oKw, oVw, sa_bk, sa_bv, KB, VB, 0, NB*HWT, 256, DIM, FLAG);
  slots_init_k<<<CDIV(NB*NSL*DIM, 256), 256, 0, stream>>>(slots_mu, slots_logsig, slot_noise, SLOTS, FLAG);

  for (int it = 0; it < 3; ++it) {
    ln512_k<<<MS, 256, 0, stream>>>(SLOTS, sa_ln_sl_g, sa_ln_sl_b, SLNB, FLAG);
    GEMMM(SLNB, 1, oQw, sa_bq, 0, QB, 0, MS, 256, DIM, 0, 0, 1);
    slot_core_k<<<16, 256, 0, stream>>>(QB, KB, VB, UPD);
    GEMMM(UPD, 0, oWo, sa_bo, 0, UPDP, 0, MS, DIM, 256, 0, 0, 1);
    gemm_mfma_duo<<<dim3(24, 4, 2), 256, 0, stream>>>(
        UPDP, SLOTS, 0, WTS, oGih, oGhh, gru_bih, gru_bhh, GX, GH, 0, MS, 1536, DIM, FLAG);
    gru_k<<<CDIV(NB*NSL*DIM, 256), 256, 0, stream>>>(GX, GH, SLOTS);
    ln512_k<<<MS, 256, 0, stream>>>(SLOTS, sa_ln_ff_g, sa_ln_ff_b, SLNB, FLAG);
    GEMMM(SLNB, 1, oMlp1, sa_mlp_b1, 0, HIDSB, 1, MS, DIM, DIM, 1, 0, 1);
    GEMMM(HIDSB, 1, oMlp2, sa_mlp_b2, 0, SLOTS, 0, MS, DIM, DIM, 0, 1, 1);
  }

  // ---- rel-pos bias ----
  s2c_k<<<MS, 256, 0, stream>>>(SLOTS, s2c_w, s2c_b, SC, FLAG);
  build_coords_k<<<CDIV(NB*NT, 256), 256, 0, stream>>>(SC, CRD);
  relpos_table_k<<<961, 128, 0, stream>>>(rp_w1, rp_b1, rp_w2, rp_b2, rp_w3, rp_b3, TAB, FLAG);
  bias_fill_k<<<CDIV(NB*NH*HWT*HWT, 256), 256, 0, stream>>>(TAB, BIAS);
  {
    unsigned short* H1 = HBB;
    unsigned short* H2 = HBB + (size_t)PCH * 128;
    for (int c = 0; c < 2; ++c) {
      int pb = c * PCH;
      rp_l1_k<<<CDIV(PCH*128, 256), 256, 0, stream>>>(CRD, rp_w1, rp_b1, H1, pb, PCH, FLAG);
      GEMMM(H1, 1, oRp2, rp_b2, 0, H2, 1, PCH, 128, 128, 3, 0, 1);
      rp_l3_k<<<CDIV(PCH,32), 256, 0, stream>>>(H2, rp_w3, rp_b3, BIAS, pb, PCH, FLAG);
    }
  }

  // ---- transformer ----
  build_x_k<<<CDIV(NB*NT*DIM, 256), 256, 0, stream>>>(SLOTS, TOK, X);
  for (int l = 0; l < 6; ++l) {
    size_t lw = (size_t)l * 512 * 512;
    rms512_k<<<MROW, 256, 0, stream>>>(X, attn_g, l * DIM, HBB, FLAG);
    gemm_mfma_tri<<<dim3(8, 20, 3), 256, 0, stream>>>(
        HBB, 1, WTS, oWq + lw, oWk + lw, oWv + lw, QHB, KHB, VHB, 1, MROW, DIM, DIM, FLAG);
    attn_fused_k<<<dim3(10, NB*NH), 256, 0, stream>>>(QHB, KHB, VHB, BIAS, OBB);
    GEMMM(OBB, 1, oWol + lw, (const void*)nullptr, 0, X, 0, MROW, DIM, DIM, 0, 1, 2);
    rms512_k<<<MROW, 256, 0, stream>>>(X, ff_g, l * DIM, HBB, FLAG);
    GEMMM(HBB, 1, oFf1 + (size_t)l * 512 * 2048, ff_b1, l * FF, FFHB, 1, MROW, FF, DIM, 2, 0, 1);
    GEMMM(FFHB, 1, oFf2 + (size_t)l * 2048 * 512, ff_b2, l * DIM, X, 0, MROW, DIM, FF, 0, 1, 4);
  }

  // ---- head (K-split 2, atomic into zeroed OUTT) ----
  rms512_k<<<MROW, 256, 0, stream>>>(X, final_g, 0, HBB, FLAG);
  hipMemsetAsync(OUTT, 0, (size_t)NB * NT * DIM * sizeof(float), stream);
  GEMMM(HBB, 1, oPred, pred_b, 0, OUTT, 0, MROW, DIM, DIM, 0, 0, 2);
  write_out_k<<<CDIV(NB*HWT*DIM, 256), 256, 0, stream>>>(OUTT, d_out, FLAG);

#undef GEMMM
}

// Round 10
// 1169.727 us; speedup vs baseline: 1.1564x; 1.1564x over previous
//
#include <hip/hip_runtime.h>
#include <hip/hip_bf16.h>

typedef __hip_bfloat16 bf16;
typedef short short8v __attribute__((ext_vector_type(8)));
typedef float float4v __attribute__((ext_vector_type(4)));

static __device__ __forceinline__ float b2f(bf16 x){ return __bfloat162float(x); }

// dtype-flexible input load: isbf ? bf16[i] : f32[i]
static __device__ __forceinline__ float ldin(const void* p, size_t i, bool isbf) {
  return isbf ? b2f(((const bf16*)p)[i]) : ((const float*)p)[i];
}

static __device__ __forceinline__ unsigned short f2bu(float f) {
  bf16 h = __float2bfloat16(f);
  return *reinterpret_cast<unsigned short*>(&h);
}

#define CDIV(a,b) (((a)+(b)-1)/(b))

// Model constants
#define NB   4
#define NSL  50
#define HWT  256
#define NT   306     // NSL + HWT
#define DIM  512
#define NH   8
#define FF   2048
#define RPP  28100   // mixed rel-pos pairs per batch
#define PCH  56200   // rel-pos chunk (2 chunks of NB*RPP/2)

// decode mixed-pair index q (0..RPP-1) -> (i,j)
static __device__ __forceinline__ void rp_decode(int q, int& i, int& j) {
  if (q < 15300) { i = q / NT; j = q % NT; }
  else { int r = q - 15300; i = NSL + r / NSL; j = r % NSL; }
}

// ---------------------------------------------------------------------------
// dtype detector (bf16 vs f32 served data); flag=1 means bf16.
// ---------------------------------------------------------------------------
__global__ void detect_k(const void* p, int* flag) {
  const unsigned short* u = (const unsigned short*)p;
  int t = threadIdx.x;
  int e = (u[t] >> 7) & 0xFF;
  __shared__ int anybad;
  if (t == 0) anybad = 0;
  __syncthreads();
  if (e >= 0x88) atomicOr(&anybad, 1);
  __syncthreads();
  if (t == 0) *flag = anybad ? 0 : 1;
}

// ---------------------------------------------------------------------------
// Batched weight transpose: all 17 weights in ONE launch.
// W[K,N] (bf16 or f32) -> WT[N,K] bf16; K,N multiples of 64; L layer slices.
// ---------------------------------------------------------------------------
struct WtArgs {
  const void* W[17];
  unsigned long long wto[17];
  int K[17], N[17];
  int base[18];
};

__global__ __launch_bounds__(256) void wtrans_all_k(WtArgs a, unsigned short* __restrict__ WT,
                                                    const int* __restrict__ flagp) {
  const bool isbf = *flagp != 0;
  int bid = blockIdx.x;
  int idx = 0;
#pragma unroll
  for (int i = 1; i < 17; ++i) if (bid >= a.base[i]) idx = i;
  int t0 = bid - a.base[idx];
  const int K = a.K[idx], N = a.N[idx];
  const int tilesN = N >> 6;
  const int perLayer = tilesN * (K >> 6);
  const int layer = t0 / perLayer, rem = t0 % perLayer;
  const int n0 = (rem % tilesN) * 64, k0 = (rem / tilesN) * 64;
  const void* W = a.W[idx];
  unsigned short* dst0 = WT + a.wto[idx];
  const size_t slice = (size_t)K * N * layer;

  __shared__ unsigned short S[64 * 72];
  int t = threadIdx.x;
  int kk = t >> 4, nn = (t & 15) * 4;
#pragma unroll
  for (int r = 0; r < 4; ++r) {
    int k = k0 + kk + r * 16;
    unsigned short v[4];
    if (isbf) {
      ushort4 u = *(const ushort4*)((const unsigned short*)W + slice + (size_t)k * N + n0 + nn);
      v[0]=u.x; v[1]=u.y; v[2]=u.z; v[3]=u.w;
    } else {
      float4 f = *(const float4*)((const float*)W + slice + (size_t)k * N + n0 + nn);
      v[0]=f2bu(f.x); v[1]=f2bu(f.y); v[2]=f2bu(f.z); v[3]=f2bu(f.w);
    }
#pragma unroll
    for (int i = 0; i < 4; ++i) S[(nn + i) * 72 + kk + r * 16] = v[i];
  }
  __syncthreads();
  int nr = t >> 2, kc = (t & 3) * 16;
  short8v s0 = *(const short8v*)&S[nr * 72 + kc];
  short8v s1 = *(const short8v*)&S[nr * 72 + kc + 8];
  unsigned short* dst = dst0 + slice + (size_t)(n0 + nr) * K + k0 + kc;
  *(short8v*)dst = s0;
  *(short8v*)(dst + 8) = s1;
}

// ---------------------------------------------------------------------------
// MFMA bf16 GEMM body v3: BK=64 (8 MFMA per barrier pair), W TRANSPOSED as
// WT[N,K] bf16. Coalesced k-contig 32B/thread staging + register prefetch.
// mode: 0=store, 1=accumulate, 2=atomicAdd (K-split). bias added iff kbeg==0.
// act: 0 none, 1 relu, 2 gelu(tanh), 3 silu. N%64==0, K%64==0.
// ---------------------------------------------------------------------------
#define LDK 72
static __device__ __forceinline__ void gemm_body2(
    const void* __restrict__ A, int aty,
    const unsigned short* __restrict__ WT,
    const void* __restrict__ bias, size_t boff,
    void* __restrict__ C, int oty,
    int M, int N, int K, int kbeg, int kend,
    int act, int mode, bool isbf)
{
  __shared__ unsigned short As[64 * LDK];
  __shared__ unsigned short Bs[64 * LDK];
  const int tid = threadIdx.x;
  const int lane = tid & 63, wave = tid >> 6;
  const int quad = lane >> 4, ti = lane & 15;
  const int wm = (wave & 1) * 32, wn = (wave >> 1) * 32;
  const int bm = blockIdx.y * 64, bn = blockIdx.x * 64;
  const int srow = tid >> 2, sch = (tid & 3) * 16;

  unsigned short ha[16], hb[16];
  const int gm = bm + srow;
  const bool aok = gm < M;
  const unsigned short* Abf = (const unsigned short*)A + (size_t)gm * K;
  const float*          Af  = (const float*)A + (size_t)gm * K;
  const unsigned short* Bp  = WT + (size_t)(bn + srow) * K;

  auto fetchA = [&](int k0) {
    if (aok) {
      if (aty) {
        const ushort4* ap = (const ushort4*)(Abf + k0 + sch);
#pragma unroll
        for (int i = 0; i < 4; ++i) {
          ushort4 u = ap[i];
          ha[i*4+0]=u.x; ha[i*4+1]=u.y; ha[i*4+2]=u.z; ha[i*4+3]=u.w;
        }
      } else {
        const float4* ap = (const float4*)(Af + k0 + sch);
#pragma unroll
        for (int i = 0; i < 4; ++i) {
          float4 f = ap[i];
          ha[i*4+0]=f2bu(f.x); ha[i*4+1]=f2bu(f.y); ha[i*4+2]=f2bu(f.z); ha[i*4+3]=f2bu(f.w);
        }
      }
    } else {
#pragma unroll
      for (int i = 0; i < 16; ++i) ha[i] = 0;
    }
  };
  auto fetchB = [&](int k0) {
    const ushort4* bp = (const ushort4*)(Bp + k0 + sch);
#pragma unroll
    for (int i = 0; i < 4; ++i) {
      ushort4 u = bp[i];
      hb[i*4+0]=u.x; hb[i*4+1]=u.y; hb[i*4+2]=u.z; hb[i*4+3]=u.w;
    }
  };

  float4v acc00 = {0,0,0,0}, acc01 = {0,0,0,0}, acc10 = {0,0,0,0}, acc11 = {0,0,0,0};
  fetchA(kbeg); fetchB(kbeg);
  for (int k0 = kbeg; k0 < kend; k0 += 64) {
    *(short8v*)&As[srow * LDK + sch]     = *(short8v*)ha;
    *(short8v*)&As[srow * LDK + sch + 8] = *(short8v*)(ha + 8);
    *(short8v*)&Bs[srow * LDK + sch]     = *(short8v*)hb;
    *(short8v*)&Bs[srow * LDK + sch + 8] = *(short8v*)(hb + 8);
    __syncthreads();
    if (k0 + 64 < kend) { fetchA(k0 + 64); fetchB(k0 + 64); }
#pragma unroll
    for (int ks = 0; ks < 2; ++ks) {
      short8v a0 = *reinterpret_cast<const short8v*>(&As[(wm + ti)      * LDK + ks * 32 + quad * 8]);
      short8v a1 = *reinterpret_cast<const short8v*>(&As[(wm + 16 + ti) * LDK + ks * 32 + quad * 8]);
      short8v b0 = *reinterpret_cast<const short8v*>(&Bs[(wn + ti)      * LDK + ks * 32 + quad * 8]);
      short8v b1 = *reinterpret_cast<const short8v*>(&Bs[(wn + 16 + ti) * LDK + ks * 32 + quad * 8]);
      acc00 = __builtin_amdgcn_mfma_f32_16x16x32_bf16(a0, b0, acc00, 0, 0, 0);
      acc01 = __builtin_amdgcn_mfma_f32_16x16x32_bf16(a0, b1, acc01, 0, 0, 0);
      acc10 = __builtin_amdgcn_mfma_f32_16x16x32_bf16(a1, b0, acc10, 0, 0, 0);
      acc11 = __builtin_amdgcn_mfma_f32_16x16x32_bf16(a1, b1, acc11, 0, 0, 0);
    }
    __syncthreads();
  }

  float4v accs[2][2] = {{acc00, acc01}, {acc10, acc11}};
#pragma unroll
  for (int mi = 0; mi < 2; ++mi) {
#pragma unroll
    for (int ni = 0; ni < 2; ++ni) {
      int row0 = bm + wm + mi * 16 + quad * 4;
      int col  = bn + wn + ni * 16 + ti;
      float bv = (bias && kbeg == 0) ? ldin(bias, boff + col, isbf) : 0.f;
#pragma unroll
      for (int r = 0; r < 4; ++r) {
        int row = row0 + r;
        if (row >= M) continue;
        float v = accs[mi][ni][r] + bv;
        if (act == 1) v = fmaxf(v, 0.f);
        else if (act == 2) {
          float u = 0.7978845608028654f * (v + 0.044715f * v * v * v);
          v = 0.5f * v * (1.f + tanhf(u));
        } else if (act == 3) {
          v = v / (1.f + expf(-v));
        }
        size_t idx = (size_t)row * N + col;
        if (oty) ((bf16*)C)[idx] = __float2bfloat16(v);
        else {
          float* Cf = (float*)C;
          if (mode == 2) atomicAdd(&Cf[idx], v);
          else if (mode == 1) Cf[idx] += v;
          else Cf[idx] = v;
        }
      }
    }
  }
}

__global__ __launch_bounds__(256) void gemm_mfma(
    const void* A, int aty, const unsigned short* WT, size_t woff,
    const void* bias, size_t boff, void* C, int oty,
    int M, int N, int K, int act, int accum, int zsplit, const int* __restrict__ flagp)
{
  int ksz = K / zsplit;
  int kbeg = blockIdx.z * ksz;
  int mode = zsplit > 1 ? 2 : (accum ? 1 : 0);
  gemm_body2(A, aty, WT + woff, bias, boff, C, oty, M, N, K, kbeg, kbeg + ksz,
             act, mode, *flagp != 0);
}

// 3 GEMMs sharing A/shapes (QKV); blockIdx.z selects job
__global__ __launch_bounds__(256) void gemm_mfma_tri(
    const void* A, int aty, const unsigned short* WT, size_t o0, size_t o1, size_t o2,
    void* C0, void* C1, void* C2, int oty, int M, int N, int K,
    const int* __restrict__ flagp)
{
  size_t o = blockIdx.z == 0 ? o0 : (blockIdx.z == 1 ? o1 : o2);
  void* C = blockIdx.z == 0 ? C0 : (blockIdx.z == 1 ? C1 : C2);
  gemm_body2(A, aty, WT + o, nullptr, 0, C, oty, M, N, K, 0, K, 0, 0, *flagp != 0);
}

// 2 GEMMs, separate A/W/bias/C, shared shapes
__global__ __launch_bounds__(256) void gemm_mfma_duo(
    const void* A0, const void* A1, int aty, const unsigned short* WT, size_t o0, size_t o1,
    const void* bias0, const void* bias1, void* C0, void* C1, int oty,
    int M, int N, int K, const int* __restrict__ flagp)
{
  const void* A = blockIdx.z ? A1 : A0;
  size_t o = blockIdx.z ? o1 : o0;
  const void* bias = blockIdx.z ? bias1 : bias0;
  void* C = blockIdx.z ? C1 : C0;
  gemm_body2(A, aty, WT + o, bias, 0, C, oty, M, N, K, 0, K, 0, 0, *flagp != 0);
}

// ---------------------------------------------------------------------------
// slot coords projection: SC[row,0:2] = SLOTS[row,:] @ s2c_w + s2c_b
// ---------------------------------------------------------------------------
__global__ void s2c_k(const float* __restrict__ slots, const void* __restrict__ w,
                      const void* __restrict__ bv, float* __restrict__ sc,
                      const int* __restrict__ flagp) {
  const bool isbf = *flagp != 0;
  int row = blockIdx.x, t = threadIdx.x;
  const float* x = slots + (size_t)row * DIM;
  float v0 = x[t], v1 = x[t + 256];
  float a0 = v0 * ldin(w, 2 * t, isbf)     + v1 * ldin(w, 2 * (t + 256), isbf);
  float a1 = v0 * ldin(w, 2 * t + 1, isbf) + v1 * ldin(w, 2 * (t + 256) + 1, isbf);
  __shared__ float r0[256], r1[256];
  r0[t] = a0; r1[t] = a1;
  __syncthreads();
  for (int o = 128; o > 0; o >>= 1) {
    if (t < o) { r0[t] += r0[t + o]; r1[t] += r1[t + o]; }
    __syncthreads();
  }
  if (t == 0) {
    sc[row * 2]     = r0[0] + ldin(bv, 0, isbf);
    sc[row * 2 + 1] = r1[0] + ldin(bv, 1, isbf);
  }
}

// ---------------------------------------------------------------------------
// Patch extraction (im2col) -> bf16
// ---------------------------------------------------------------------------
__global__ void patchify_k(const void* __restrict__ img, unsigned short* __restrict__ xp,
                           const int* __restrict__ flagp) {
  const bool isbf = *flagp != 0;
  int i = blockIdx.x * 256 + threadIdx.x;
  if (i >= NB * HWT * 768) return;
  int col = i % 768, row = i / 768;
  int c = col % 3, p2 = (col / 3) & 15, p1 = col / 48;
  int w = row & 15, h = (row >> 4) & 15, b = row >> 8;
  xp[i] = f2bu(ldin(img, (((size_t)(b * 3 + c) * 256 + h * 16 + p1) * 256) + w * 16 + p2, isbf));
}

__global__ void addpos_k(float* __restrict__ tok, const void* __restrict__ hp,
                         const void* __restrict__ wp, const int* __restrict__ flagp) {
  const bool isbf = *flagp != 0;
  int i = blockIdx.x * 256 + threadIdx.x;
  if (i >= NB * HWT * DIM) return;
  int d = i & 511;
  int row = i >> 9;
  int w = row & 15, h = (row >> 4) & 15;
  tok[i] += ldin(hp, h * DIM + d, isbf) + ldin(wp, w * DIM + d, isbf);
}

// ---------------------------------------------------------------------------
// LayerNorm (bf16 out) / RMSNorm (bf16 out) over 512-dim rows
// ---------------------------------------------------------------------------
__global__ void ln512_k(const float* __restrict__ X, const void* __restrict__ g,
                        const void* __restrict__ b, unsigned short* __restrict__ Y,
                        const int* __restrict__ flagp) {
  const bool isbf = *flagp != 0;
  int row = blockIdx.x, t = threadIdx.x;
  const float* x = X + (size_t)row * DIM;
  float v0 = x[t], v1 = x[t + 256];
  __shared__ float rs[256], rq[256];
  rs[t] = v0 + v1; rq[t] = v0 * v0 + v1 * v1;
  __syncthreads();
  for (int o = 128; o > 0; o >>= 1) {
    if (t < o) { rs[t] += rs[t + o]; rq[t] += rq[t + o]; }
    __syncthreads();
  }
  float mean = rs[0] * (1.f / 512.f);
  float var  = rq[0] * (1.f / 512.f) - mean * mean;
  float inv  = rsqrtf(var + 1e-5f);
  unsigned short* y = Y + (size_t)row * DIM;
  y[t]       = f2bu((v0 - mean) * inv * ldin(g, t, isbf)       + ldin(b, t, isbf));
  y[t + 256] = f2bu((v1 - mean) * inv * ldin(g, t + 256, isbf) + ldin(b, t + 256, isbf));
}

__global__ void rms512_k(const float* __restrict__ X, const void* __restrict__ g,
                         int goff, unsigned short* __restrict__ Y, const int* __restrict__ flagp) {
  const bool isbf = *flagp != 0;
  int row = blockIdx.x, t = threadIdx.x;
  const float* x = X + (size_t)row * DIM;
  float v0 = x[t], v1 = x[t + 256];
  __shared__ float rq[256];
  rq[t] = v0 * v0 + v1 * v1;
  __syncthreads();
  for (int o = 128; o > 0; o >>= 1) {
    if (t < o) rq[t] += rq[t + o];
    __syncthreads();
  }
  float nrm = sqrtf(rq[0]);
  float sc = 22.62741699796952f / fmaxf(nrm, 1e-12f);
  unsigned short* y = Y + (size_t)row * DIM;
  y[t]       = f2bu(v0 * sc * ldin(g, goff + t, isbf));
  y[t + 256] = f2bu(v1 * sc * ldin(g, goff + t + 256, isbf));
}

// ---------------------------------------------------------------------------
// Slot attention (separate kernels — high occupancy)
// ---------------------------------------------------------------------------
__global__ void slots_init_k(const void* __restrict__ mu, const void* __restrict__ ls,
                             const void* __restrict__ noise, float* __restrict__ slots,
                             const int* __restrict__ flagp) {
  const bool isbf = *flagp != 0;
  int i = blockIdx.x * 256 + threadIdx.x;
  if (i >= NB * NSL * DIM) return;
  int d = i & 511;
  slots[i] = ldin(mu, d, isbf) + expf(ldin(ls, d, isbf)) * ldin(noise, i, isbf);
}

__global__ void slot_dots_k(const float* __restrict__ q, const float* __restrict__ k,
                            float* __restrict__ dots) {
  int blk = blockIdx.x;                 // b*200 + h*50 + i
  int i = blk % 50, h = (blk / 50) & 3, b = blk / 200;
  int j = threadIdx.x;
  __shared__ float qs[64];
  if (threadIdx.x < 64) qs[threadIdx.x] = q[((size_t)(b * 50 + i)) * 256 + h * 64 + threadIdx.x];
  __syncthreads();
  const float* kr = k + ((size_t)(b * 256 + j)) * 256 + h * 64;
  float s = 0.f;
#pragma unroll 8
  for (int d = 0; d < 64; ++d) s = fmaf(qs[d], kr[d], s);
  dots[(((size_t)(b * 4 + h) * 50) + i) * 256 + j] = s * 0.125f;
}

__global__ void softmax_slots_k(float* __restrict__ dots) {
  int idx = blockIdx.x * 256 + threadIdx.x;
  if (idx >= 4096) return;
  int j = idx & 255, h = (idx >> 8) & 3, b = idx >> 10;
  float* base = dots + ((size_t)(b * 4 + h) * 50) * 256 + j;
  float m = -1e30f;
  for (int i = 0; i < 50; ++i) m = fmaxf(m, base[i * 256]);
  float s = 0.f;
  for (int i = 0; i < 50; ++i) { float e = expf(base[i * 256] - m); base[i * 256] = e; s += e; }
  float inv = 1.f / s;
  for (int i = 0; i < 50; ++i) base[i * 256] *= inv;
}

__global__ void renorm_attn_k(float* __restrict__ attn) {
  int t = threadIdx.x;
  float* row = attn + (size_t)blockIdx.x * 256;
  float v = row[t] + 1e-8f;
  __shared__ float rs[256];
  rs[t] = v;
  __syncthreads();
  for (int o = 128; o > 0; o >>= 1) {
    if (t < o) rs[t] += rs[t + o];
    __syncthreads();
  }
  row[t] = v / rs[0];
}

__global__ void slot_upd_k(const float* __restrict__ attn, const float* __restrict__ v,
                           float* __restrict__ upd) {
  int bi = blockIdx.x;        // b*50+i
  int b = bi / 50, i = bi % 50;
  int t = threadIdx.x, h = t >> 6;
  const float* arow = attn + ((size_t)((b * 4 + h) * 50) + i) * 256;
  float s = 0.f;
  for (int j = 0; j < 256; ++j) s = fmaf(arow[j], v[((size_t)(b * 256 + j)) * 256 + t], s);
  upd[(size_t)bi * 256 + t] = s;
}

// in-place safe (elementwise)
__global__ void gru_k(const float* __restrict__ gx, const float* __restrict__ gh,
                      float* __restrict__ slots) {
  int i = blockIdx.x * 256 + threadIdx.x;
  if (i >= NB * NSL * DIM) return;
  int row = i >> 9, d = i & 511;
  size_t b3 = (size_t)row * 1536;
  float xr = gx[b3 + d], xz = gx[b3 + 512 + d], xn = gx[b3 + 1024 + d];
  float hr = gh[b3 + d], hz = gh[b3 + 512 + d], hn = gh[b3 + 1024 + d];
  float r = 1.f / (1.f + expf(-(xr + hr)));
  float z = 1.f / (1.f + expf(-(xz + hz)));
  float n = tanhf(xn + r * hn);
  float prev = slots[i];
  slots[i] = (1.f - z) * n + z * prev;
}

// ---------------------------------------------------------------------------
// Rel-pos bias
// ---------------------------------------------------------------------------
__global__ void build_coords_k(const float* __restrict__ sc, float* __restrict__ coords) {
  int i = blockIdx.x * 256 + threadIdx.x;
  if (i >= NB * NT) return;
  int b = i / NT, n = i % NT;
  float cx, cy;
  if (n < NSL) { cx = sc[(b * NSL + n) * 2]; cy = sc[(b * NSL + n) * 2 + 1]; }
  else { int t = n - NSL; cx = (float)(t >> 4); cy = (float)(t & 15); }
  coords[i * 2] = cx; coords[i * 2 + 1] = cy;
}

__global__ void relpos_table_k(const void* w1, const void* b1, const void* w2,
                               const void* b2, const void* w3, const void* b3,
                               float* __restrict__ tab, const int* __restrict__ flagp) {
  const bool isbf = *flagp != 0;
  int blk = blockIdx.x;  // 961
  float r0 = (float)(blk / 31 - 15), r1 = (float)(blk % 31 - 15);
  int t = threadIdx.x;
  __shared__ float h1[128], h2[128];
  float a = fmaf(r0, ldin(w1, t, isbf), fmaf(r1, ldin(w1, 128 + t, isbf), ldin(b1, t, isbf)));
  h1[t] = a / (1.f + expf(-a));
  __syncthreads();
  float s = ldin(b2, t, isbf);
#pragma unroll 4
  for (int k = 0; k < 128; ++k) s = fmaf(h1[k], ldin(w2, k * 128 + t, isbf), s);
  h2[t] = s / (1.f + expf(-s));
  __syncthreads();
  if (t < 8) {
    float o = ldin(b3, t, isbf);
#pragma unroll 4
    for (int k = 0; k < 128; ++k) o = fmaf(h2[k], ldin(w3, k * 8 + t, isbf), o);
    tab[blk * 8 + t] = o;
  }
}

__global__ void bias_fill_k(const float* __restrict__ tab, float* __restrict__ bias) {
  int i = blockIdx.x * 256 + threadIdx.x;
  if (i >= NB * NH * HWT * HWT) return;
  int jj = i & 255, ii = (i >> 8) & 255, h = (i >> 16) & 7, b = i >> 19;
  int di = (ii >> 4) - (jj >> 4) + 15;
  int dj = (ii & 15) - (jj & 15) + 15;
  bias[(((size_t)(b * NH + h) * NT) + NSL + ii) * NT + NSL + jj] = tab[(di * 31 + dj) * 8 + h];
}

// layer1 silu -> H1 bf16 [pcount,128], chunked
__global__ void rp_l1_k(const float* __restrict__ coords, const void* w1, const void* b1,
                        unsigned short* __restrict__ H, int pbase, int pcount,
                        const int* __restrict__ flagp) {
  const bool isbf = *flagp != 0;
  int idx = blockIdx.x * 256 + threadIdx.x;
  if (idx >= pcount * 128) return;
  int pl = idx >> 7, u = idx & 127;
  int p = pbase + pl;
  int q = p % RPP, bb = p / RPP;
  int ii, jj;
  rp_decode(q, ii, jj);
  float r0 = coords[(bb * NT + ii) * 2]     - coords[(bb * NT + jj) * 2];
  float r1 = coords[(bb * NT + ii) * 2 + 1] - coords[(bb * NT + jj) * 2 + 1];
  float a = fmaf(r0, ldin(w1, u, isbf), fmaf(r1, ldin(w1, 128 + u, isbf), ldin(b1, u, isbf)));
  H[(size_t)pl * 128 + u] = f2bu(a / (1.f + expf(-a)));
}

// layer3 (128->8) + scatter. 32 pairs/block, 8 threads/pair.
__global__ __launch_bounds__(256) void rp_l3_k(
    const unsigned short* __restrict__ H2, const void* w3, const void* b3,
    float* __restrict__ bias, int pbase, int pcount, const int* __restrict__ flagp) {
  const bool isbf = *flagp != 0;
  __shared__ float W3s[128 * 8];
  int t = threadIdx.x;
  for (int e = t; e < 1024; e += 256) W3s[e] = ldin(w3, e, isbf);
  __syncthreads();
  int pl = blockIdx.x * 32 + (t >> 3), hh = t & 7;
  if (pl >= pcount) return;
  int p = pbase + pl;
  int q = p % RPP, bb = p / RPP;
  int ii, jj;
  rp_decode(q, ii, jj);
  float s = ldin(b3, hh, isbf);
  const unsigned short* hrow = H2 + (size_t)pl * 128;
#pragma unroll 8
  for (int k = 0; k < 128; ++k) {
    bf16 hv = *reinterpret_cast<const bf16*>(&hrow[k]);
    s = fmaf(b2f(hv), W3s[k * 8 + hh], s);
  }
  bias[((size_t)(bb * NH + hh) * NT + ii) * NT + jj] = s;
}

// ---------------------------------------------------------------------------
// Transformer pieces
// ---------------------------------------------------------------------------
__global__ void build_x_k(const float* __restrict__ slots, const float* __restrict__ tok,
                          float* __restrict__ x) {
  int i = blockIdx.x * 256 + threadIdx.x;
  if (i >= NB * NT * DIM) return;
  int d = i & 511, n = (i >> 9) % NT, b = i / (NT * DIM);
  x[i] = (n < NSL) ? slots[((size_t)(b * NSL + n)) * DIM + d]
                   : tok[((size_t)(b * HWT + (n - NSL))) * DIM + d];
}

// ---------------------------------------------------------------------------
// Fused attention: per block = 32 q-rows x one (b,h). S = QK^T*0.125 + bias
// (f32 LDS), in-block softmax (8 lanes/row), P bf16 in place, O = P V.
// grid (10, 32). LDS ~56 KB.
// ---------------------------------------------------------------------------
__global__ __launch_bounds__(256) void attn_fused_k(
    const unsigned short* __restrict__ Qb, const unsigned short* __restrict__ Kb,
    const unsigned short* __restrict__ Vb, const float* __restrict__ bias,
    unsigned short* __restrict__ Ob)
{
  const int bh = blockIdx.y, b = bh >> 3, h = bh & 7;
  const int i0 = blockIdx.x * 32;
  __shared__ unsigned short Qs[32 * 72];
  __shared__ unsigned short Ks[64 * 72];
  __shared__ float S[32 * 332];
  unsigned short* P = (unsigned short*)S;   // bf16 prob, row stride 664 shorts

  const int tid = threadIdx.x;
  const int lane = tid & 63, wave = tid >> 6, quad = lane >> 4, ti = lane & 15;
  const int mi = wave & 1, nh = wave >> 1;

  // ---- load Q tile (32 x 64) ----
  {
    int r = tid >> 3, c = (tid & 7) * 8;
    int gi = i0 + r;
    ushort4 u0 = {0,0,0,0}, u1 = {0,0,0,0};
    if (gi < NT) {
      const ushort4* p = (const ushort4*)(Qb + ((size_t)(b * NT + gi)) * DIM + h * 64 + c);
      u0 = p[0]; u1 = p[1];
    }
    *(ushort4*)&Qs[r * 72 + c] = u0;
    *(ushort4*)&Qs[r * 72 + c + 4] = u1;
  }

  // ---- phase 1: scores ----
  for (int kt = 0; kt < 5; ++kt) {
    __syncthreads();
    {
      int kr = tid >> 2, c = (tid & 3) * 16;
      int gj = kt * 64 + kr;
      ushort4 v[4] = {{0,0,0,0},{0,0,0,0},{0,0,0,0},{0,0,0,0}};
      if (gj < NT) {
        const ushort4* p = (const ushort4*)(Kb + ((size_t)(b * NT + gj)) * DIM + h * 64 + c);
#pragma unroll
        for (int i = 0; i < 4; ++i) v[i] = p[i];
      }
#pragma unroll
      for (int i = 0; i < 4; ++i) *(ushort4*)&Ks[kr * 72 + c + i * 4] = v[i];
    }
    __syncthreads();
#pragma unroll
    for (int ntl = 0; ntl < 2; ++ntl) {
      int nt = nh * 2 + ntl;
      float4v acc = {0,0,0,0};
#pragma unroll
      for (int ks = 0; ks < 2; ++ks) {
        short8v a  = *(const short8v*)&Qs[(mi * 16 + ti) * 72 + ks * 32 + quad * 8];
        short8v bb = *(const short8v*)&Ks[(nt * 16 + ti) * 72 + ks * 32 + quad * 8];
        acc = __builtin_amdgcn_mfma_f32_16x16x32_bf16(a, bb, acc, 0, 0, 0);
      }
      int colL = kt * 64 + nt * 16 + ti;
      int row0 = mi * 16 + quad * 4;
#pragma unroll
      for (int r = 0; r < 4; ++r) {
        int row_g = i0 + row0 + r;
        float val;
        if (colL < NT) {
          float bv = (row_g < NT) ? bias[((size_t)bh * NT + row_g) * NT + colL] : 0.f;
          val = acc[r] * 0.125f + bv;
        } else val = -1e30f;
        S[(row0 + r) * 332 + colL] = val;
      }
    }
  }
  __syncthreads();

  // ---- phase 2: softmax (rows in regs), write P bf16 in place ----
  {
    int rl = tid >> 3, sub = tid & 7;
    float sv[40];
#pragma unroll
    for (int k = 0; k < 40; ++k) sv[k] = S[rl * 332 + sub + k * 8];
    float m = -1e30f;
#pragma unroll
    for (int k = 0; k < 40; ++k) m = fmaxf(m, sv[k]);
    m = fmaxf(m, __shfl_xor(m, 1));
    m = fmaxf(m, __shfl_xor(m, 2));
    m = fmaxf(m, __shfl_xor(m, 4));
    float s = 0.f;
#pragma unroll
    for (int k = 0; k < 40; ++k) { float e = __expf(sv[k] - m); sv[k] = e; s += e; }
    s += __shfl_xor(s, 1);
    s += __shfl_xor(s, 2);
    s += __shfl_xor(s, 4);
    float inv = 1.f / s;
    __syncthreads();   // all S reads complete before bf16 overwrite
#pragma unroll
    for (int k = 0; k < 40; ++k) P[rl * 664 + sub + k * 8] = f2bu(sv[k] * inv);
  }

  // ---- phase 3: O = P V ----
  float4v oacc[2] = {{0,0,0,0},{0,0,0,0}};
  for (int vt = 0; vt < 5; ++vt) {
    __syncthreads();
    {
      int key = tid & 63, d0 = (tid >> 6) * 16;
      int gj = vt * 64 + key;
      unsigned short hv[16];
      if (gj < NT) {
        const ushort4* p = (const ushort4*)(Vb + ((size_t)(b * NT + gj)) * DIM + h * 64 + d0);
#pragma unroll
        for (int i = 0; i < 4; ++i) {
          ushort4 u = p[i];
          hv[i*4+0]=u.x; hv[i*4+1]=u.y; hv[i*4+2]=u.z; hv[i*4+3]=u.w;
        }
      } else {
#pragma unroll
        for (int i = 0; i < 16; ++i) hv[i] = 0;
      }
#pragma unroll
      for (int i = 0; i < 16; ++i) Ks[(d0 + i) * 72 + key] = hv[i];
    }
    __syncthreads();
#pragma unroll
    for (int ntl = 0; ntl < 2; ++ntl) {
      int nt = nh * 2 + ntl;
#pragma unroll
      for (int ks = 0; ks < 2; ++ks) {
        short8v a  = *(const short8v*)&P[(mi * 16 + ti) * 664 + vt * 64 + ks * 32 + quad * 8];
        short8v bb = *(const short8v*)&Ks[(nt * 16 + ti) * 72 + ks * 32 + quad * 8];
        oacc[ntl] = __builtin_amdgcn_mfma_f32_16x16x32_bf16(a, bb, oacc[ntl], 0, 0, 0);
      }
    }
  }

  // ---- write O ----
#pragma unroll
  for (int ntl = 0; ntl < 2; ++ntl) {
    int dim = nh * 32 + ntl * 16 + ti;
#pragma unroll
    for (int r = 0; r < 4; ++r) {
      int row_g = i0 + mi * 16 + quad * 4 + r;
      if (row_g < NT)
        Ob[((size_t)(b * NT + row_g)) * DIM + h * 64 + dim] = f2bu(oacc[ntl][r]);
    }
  }
}

__global__ void write_out_k(const float* __restrict__ tmp, void* __restrict__ out,
                            const int* __restrict__ flagp) {
  const bool isbf = *flagp != 0;
  int i = blockIdx.x * 256 + threadIdx.x;
  if (i >= NB * HWT * DIM) return;
  int d = i & 511, tt = (i >> 9) & 255, b = i / (HWT * DIM);
  float v = tmp[((size_t)(b * NT + NSL + tt)) * DIM + d];
  if (isbf) ((bf16*)out)[i] = __float2bfloat16(v);
  else      ((float*)out)[i] = v;
}

// ---------------------------------------------------------------------------
extern "C" void kernel_launch(void* const* d_in, const int* in_sizes, int n_in,
                              void* d_out, int out_size, void* d_ws, size_t ws_size,
                              hipStream_t stream) {
  const void* images        = d_in[0];
  const void* slot_noise    = d_in[1];
  const void* patch_w       = d_in[2];
  const void* patch_b       = d_in[3];
  const void* hpos          = d_in[4];
  const void* wpos          = d_in[5];
  const void* rp_w1         = d_in[6];
  const void* rp_b1         = d_in[7];
  const void* rp_w2         = d_in[8];
  const void* rp_b2         = d_in[9];
  const void* rp_w3         = d_in[10];
  const void* rp_b3         = d_in[11];
  const void* slots_mu      = d_in[12];
  const void* slots_logsig  = d_in[13];
  const void* sa_ln_in_g    = d_in[14];
  const void* sa_ln_in_b    = d_in[15];
  const void* sa_ln_sl_g    = d_in[16];
  const void* sa_ln_sl_b    = d_in[17];
  const void* sa_wq         = d_in[18];
  const void* sa_bq         = d_in[19];
  const void* sa_wk         = d_in[20];
  const void* sa_bk         = d_in[21];
  const void* sa_wv         = d_in[22];
  const void* sa_bv         = d_in[23];
  const void* sa_wo         = d_in[24];
  const void* sa_bo         = d_in[25];
  const void* gru_wih       = d_in[26];
  const void* gru_whh       = d_in[27];
  const void* gru_bih       = d_in[28];
  const void* gru_bhh       = d_in[29];
  const void* sa_ln_ff_g    = d_in[30];
  const void* sa_ln_ff_b    = d_in[31];
  const void* sa_mlp_w1     = d_in[32];
  const void* sa_mlp_b1     = d_in[33];
  const void* sa_mlp_w2     = d_in[34];
  const void* sa_mlp_b2     = d_in[35];
  const void* s2c_w         = d_in[36];
  const void* s2c_b         = d_in[37];
  const void* attn_g        = d_in[38];
  const void* wq            = d_in[39];
  const void* wk            = d_in[40];
  const void* wv            = d_in[41];
  const void* wo            = d_in[42];
  const void* ff_g          = d_in[43];
  const void* ff_w1         = d_in[44];
  const void* ff_b1         = d_in[45];
  const void* ff_w2         = d_in[46];
  const void* ff_b2         = d_in[47];
  const void* final_g       = d_in[48];
  const void* pred_w        = d_in[49];
  const void* pred_b        = d_in[50];

  float* ws = (float*)d_ws;
  int* FLAG = (int*)ws;
  size_t off = 16;
  auto alloc = [&](size_t n) { float* p = ws + off; off += (n + 15) & ~(size_t)15; return p; };
  float* TOK   = alloc((size_t)NB * HWT * DIM);
  unsigned short* INPB = (unsigned short*)alloc((size_t)NB * HWT * DIM / 2);
  float* KB    = alloc((size_t)NB * HWT * 256);
  float* VB    = alloc((size_t)NB * HWT * 256);
  float* SLOTS = alloc((size_t)NB * NSL * DIM);
  unsigned short* SLNB = (unsigned short*)alloc((size_t)NB * NSL * DIM / 2);
  float* QB    = alloc((size_t)NB * NSL * 256);
  float* ATT   = alloc((size_t)NB * 4 * NSL * HWT);
  float* UPD   = alloc((size_t)NB * NSL * 256);
  float* UPDP  = alloc((size_t)NB * NSL * DIM);
  unsigned short* HIDSB = (unsigned short*)alloc((size_t)NB * NSL * DIM / 2);
  float* SC    = alloc((size_t)NB * NSL * 2);
  float* CRD   = alloc((size_t)NB * NT * 2);
  float* TAB   = alloc((size_t)961 * 8);
  float* BIAS  = alloc((size_t)NB * NH * NT * NT);
  float* X     = alloc((size_t)NB * NT * DIM);
  // attention-region (contiguous; aliased by rel-pos H1/H2 chunks)
  unsigned short* HBB  = (unsigned short*)alloc((size_t)NB * NT * DIM / 2);
  unsigned short* QHB  = (unsigned short*)alloc((size_t)NB * NT * DIM / 2);
  unsigned short* KHB  = (unsigned short*)alloc((size_t)NB * NT * DIM / 2);
  unsigned short* VHB  = (unsigned short*)alloc((size_t)NB * NT * DIM / 2);
  float* SIM   = alloc((size_t)NB * NH * NT * NT);        // GRU-gate + rel-pos alias space
  unsigned short* OBB  = (unsigned short*)alloc((size_t)NB * NT * DIM / 2);
  unsigned short* FFHB = (unsigned short*)alloc((size_t)NB * NT * FF / 2);
  float* OUTT  = alloc((size_t)NB * NT * DIM);
  // aliases (dead-region reuse)
  unsigned short* XPB = (unsigned short*)OUTT;            // im2col; dead before head
  float* GX = SIM;                                        // GRU gates; dead before transformer
  float* GH = SIM + (size_t)NB * NSL * 1536;
  // transposed-weight arena (bf16 [N,K] per weight)
  const size_t oPatch = 0;
  const size_t oKw    = oPatch + (size_t)512 * 768;
  const size_t oVw    = oKw    + (size_t)256 * 512;
  const size_t oQw    = oVw    + (size_t)256 * 512;
  const size_t oWo    = oQw    + (size_t)256 * 512;
  const size_t oGih   = oWo    + (size_t)512 * 256;
  const size_t oGhh   = oGih   + (size_t)1536 * 512;
  const size_t oMlp1  = oGhh   + (size_t)1536 * 512;
  const size_t oMlp2  = oMlp1  + (size_t)512 * 512;
  const size_t oRp2   = oMlp2  + (size_t)512 * 512;
  const size_t oWq    = oRp2   + (size_t)128 * 128;
  const size_t oWk    = oWq    + (size_t)6 * 512 * 512;
  const size_t oWv    = oWk    + (size_t)6 * 512 * 512;
  const size_t oWol   = oWv    + (size_t)6 * 512 * 512;
  const size_t oFf1   = oWol   + (size_t)6 * 512 * 512;
  const size_t oFf2   = oFf1   + (size_t)6 * 512 * 2048;
  const size_t oPred  = oFf2   + (size_t)6 * 2048 * 512;
  const size_t wtTotal = oPred + (size_t)512 * 512;
  unsigned short* WTS = (unsigned short*)alloc((wtTotal + 1) / 2);
  (void)ws_size; (void)in_sizes; (void)n_in; (void)out_size;

#define GEMMM(A_, ATY_, WOFF_, BIAS_, BOFF_, C_, OTY_, M_, N_, K_, ACT_, ACC_, ZS_) \
  gemm_mfma<<<dim3((N_)/64, CDIV((M_),64), (ZS_)), 256, 0, stream>>>( \
      A_, ATY_, WTS, (size_t)(WOFF_), BIAS_, (size_t)(BOFF_), C_, OTY_, M_, N_, K_, ACT_, ACC_, ZS_, FLAG)

  const int MROW = NB * NT;   // 1224
  const int MS   = NB * NSL;  // 200

  // ---- dtype detection + batched weight transpose (1 launch) ----
  detect_k<<<1, 256, 0, stream>>>(images, FLAG);
  {
    WtArgs a;
    const void* Wp[17] = { patch_w, sa_wk, sa_wv, sa_wq, sa_wo, gru_wih, gru_whh,
                           sa_mlp_w1, sa_mlp_w2, rp_w2, wq, wk, wv, wo, ff_w1, ff_w2, pred_w };
    const size_t Oo[17] = { oPatch, oKw, oVw, oQw, oWo, oGih, oGhh,
                            oMlp1, oMlp2, oRp2, oWq, oWk, oWv, oWol, oFf1, oFf2, oPred };
    const int Kk[17] = {768,512,512,512,256,512,512,512,512,128,512,512,512,512,512,2048,512};
    const int Nn[17] = {512,256,256,256,512,1536,1536,512,512,128,512,512,512,512,2048,512,512};
    const int Ll[17] = {1,1,1,1,1,1,1,1,1,1,6,6,6,6,6,6,1};
    int acc = 0;
    for (int i = 0; i < 17; ++i) {
      a.W[i] = Wp[i]; a.wto[i] = Oo[i]; a.K[i] = Kk[i]; a.N[i] = Nn[i];
      a.base[i] = acc;
      acc += Ll[i] * (Kk[i] >> 6) * (Nn[i] >> 6);
    }
    a.base[17] = acc;
    wtrans_all_k<<<acc, 256, 0, stream>>>(a, WTS, FLAG);
  }

  // ---- patch embed (K-split 3, atomic into zeroed TOK) ----
  patchify_k<<<CDIV(NB*HWT*768, 256), 256, 0, stream>>>(images, XPB, FLAG);
  hipMemsetAsync(TOK, 0, (size_t)NB * HWT * DIM * sizeof(float), stream);
  GEMMM(XPB, 1, oPatch, patch_b, 0, TOK, 0, NB*HWT, DIM, 768, 0, 0, 3);
  addpos_k<<<CDIV(NB*HWT*DIM, 256), 256, 0, stream>>>(TOK, hpos, wpos, FLAG);

  // ---- slot attention: k, v ----
  ln512_k<<<NB*HWT, 256, 0, stream>>>(TOK, sa_ln_in_g, sa_ln_in_b, INPB, FLAG);
  gemm_mfma_duo<<<dim3(4, 16, 2), 256, 0, stream>>>(
      INPB, INPB, 1, WTS, oKw, oVw, sa_bk, sa_bv, KB, VB, 0, NB*HWT, 256, DIM, FLAG);
  slots_init_k<<<CDIV(NB*NSL*DIM, 256), 256, 0, stream>>>(slots_mu, slots_logsig, slot_noise, SLOTS, FLAG);

  for (int it = 0; it < 3; ++it) {
    ln512_k<<<MS, 256, 0, stream>>>(SLOTS, sa_ln_sl_g, sa_ln_sl_b, SLNB, FLAG);
    GEMMM(SLNB, 1, oQw, sa_bq, 0, QB, 0, MS, 256, DIM, 0, 0, 1);
    slot_dots_k<<<NB*4*NSL, 256, 0, stream>>>(QB, KB, ATT);
    softmax_slots_k<<<16, 256, 0, stream>>>(ATT);
    renorm_attn_k<<<NB*4*NSL, 256, 0, stream>>>(ATT);
    slot_upd_k<<<MS, 256, 0, stream>>>(ATT, VB, UPD);
    GEMMM(UPD, 0, oWo, sa_bo, 0, UPDP, 0, MS, DIM, 256, 0, 0, 1);
    gemm_mfma_duo<<<dim3(24, 4, 2), 256, 0, stream>>>(
        UPDP, SLOTS, 0, WTS, oGih, oGhh, gru_bih, gru_bhh, GX, GH, 0, MS, 1536, DIM, FLAG);
    gru_k<<<CDIV(NB*NSL*DIM, 256), 256, 0, stream>>>(GX, GH, SLOTS);
    ln512_k<<<MS, 256, 0, stream>>>(SLOTS, sa_ln_ff_g, sa_ln_ff_b, SLNB, FLAG);
    GEMMM(SLNB, 1, oMlp1, sa_mlp_b1, 0, HIDSB, 1, MS, DIM, DIM, 1, 0, 1);
    GEMMM(HIDSB, 1, oMlp2, sa_mlp_b2, 0, SLOTS, 0, MS, DIM, DIM, 0, 1, 1);
  }

  // ---- rel-pos bias ----
  s2c_k<<<MS, 256, 0, stream>>>(SLOTS, s2c_w, s2c_b, SC, FLAG);
  build_coords_k<<<CDIV(NB*NT, 256), 256, 0, stream>>>(SC, CRD);
  relpos_table_k<<<961, 128, 0, stream>>>(rp_w1, rp_b1, rp_w2, rp_b2, rp_w3, rp_b3, TAB, FLAG);
  bias_fill_k<<<CDIV(NB*NH*HWT*HWT, 256), 256, 0, stream>>>(TAB, BIAS);
  {
    unsigned short* H1 = HBB;
    unsigned short* H2 = HBB + (size_t)PCH * 128;
    for (int c = 0; c < 2; ++c) {
      int pb = c * PCH;
      rp_l1_k<<<CDIV(PCH*128, 256), 256, 0, stream>>>(CRD, rp_w1, rp_b1, H1, pb, PCH, FLAG);
      GEMMM(H1, 1, oRp2, rp_b2, 0, H2, 1, PCH, 128, 128, 3, 0, 1);
      rp_l3_k<<<CDIV(PCH,32), 256, 0, stream>>>(H2, rp_w3, rp_b3, BIAS, pb, PCH, FLAG);
    }
  }

  // ---- transformer ----
  build_x_k<<<CDIV(NB*NT*DIM, 256), 256, 0, stream>>>(SLOTS, TOK, X);
  for (int l = 0; l < 6; ++l) {
    size_t lw = (size_t)l * 512 * 512;
    rms512_k<<<MROW, 256, 0, stream>>>(X, attn_g, l * DIM, HBB, FLAG);
    gemm_mfma_tri<<<dim3(8, 20, 3), 256, 0, stream>>>(
        HBB, 1, WTS, oWq + lw, oWk + lw, oWv + lw, QHB, KHB, VHB, 1, MROW, DIM, DIM, FLAG);
    attn_fused_k<<<dim3(10, NB*NH), 256, 0, stream>>>(QHB, KHB, VHB, BIAS, OBB);
    GEMMM(OBB, 1, oWol + lw, (const void*)nullptr, 0, X, 0, MROW, DIM, DIM, 0, 1, 2);
    rms512_k<<<MROW, 256, 0, stream>>>(X, ff_g, l * DIM, HBB, FLAG);
    GEMMM(HBB, 1, oFf1 + (size_t)l * 512 * 2048, ff_b1, l * FF, FFHB, 1, MROW, FF, DIM, 2, 0, 1);
    GEMMM(FFHB, 1, oFf2 + (size_t)l * 2048 * 512, ff_b2, l * DIM, X, 0, MROW, DIM, FF, 0, 1, 4);
  }

  // ---- head (K-split 2, atomic into zeroed OUTT) ----
  rms512_k<<<MROW, 256, 0, stream>>>(X, final_g, 0, HBB, FLAG);
  hipMemsetAsync(OUTT, 0, (size_t)NB * NT * DIM * sizeof(float), stream);
  GEMMM(HBB, 1, oPred, pred_b, 0, OUTT, 0, MROW, DIM, DIM, 0, 0, 2);
  write_out_k<<<CDIV(NB*HWT*DIM, 256), 256, 0, stream>>>(OUTT, d_out, FLAG);

#undef GEMMM
}